// Round 8
// baseline (167.670 us; speedup 1.0000x reference)
//
#include <hip/hip_runtime.h>

#define B_ 4
#define C_ 256
#define CI_ 128
#define HW_ 4096
#define KS_ 6
#define LOG2E 1.44269504f

typedef _Float16 f16x8 __attribute__((ext_vector_type(8)));
typedef _Float16 f16x4 __attribute__((ext_vector_type(4)));
typedef _Float16 f16x2 __attribute__((ext_vector_type(2)));
typedef __fp16 fp16x2 __attribute__((ext_vector_type(2)));
typedef float f32x16 __attribute__((ext_vector_type(16)));
typedef float f32x4 __attribute__((ext_vector_type(4)));

__device__ __forceinline__ f32x16 mfma16(f16x8 a, f16x8 b, f32x16 c) {
  return __builtin_amdgcn_mfma_f32_32x32x16_f16(a, b, c, 0, 0, 0);
}
__device__ __forceinline__ f16x8 cat8(f16x4 a, f16x4 b) {
  return __builtin_shufflevector(a, b, 0, 1, 2, 3, 4, 5, 6, 7);
}
__device__ __forceinline__ f16x4 pk4(float a, float b, float c, float d) {
  union { fp16x2 p[2]; f16x4 v; } u;
  u.p[0] = __builtin_amdgcn_cvt_pkrtz(a, b);
  u.p[1] = __builtin_amdgcn_cvt_pkrtz(c, d);
  return u.v;
}
__device__ __forceinline__ float fmax3(float a, float b, float c) {
  return fmaxf(fmaxf(a, b), c);  // clang fuses to v_max3_f32
}
union QW { f16x4 v; long long q; };
union F4 { f16x4 v; f16x2 h2[2]; };

// Cross-half (lane ^ 32) reduce via permlane32_swap(x,x): the two outputs are
// {bcast_lo(x), bcast_hi(x)} in SOME order (robust to either swap direction).
__device__ __forceinline__ float xhalf_max(float x) {
#if __has_builtin(__builtin_amdgcn_permlane32_swap)
  auto r = __builtin_amdgcn_permlane32_swap(
      __builtin_bit_cast(unsigned, x), __builtin_bit_cast(unsigned, x), false, false);
  unsigned long long q = __builtin_bit_cast(unsigned long long, r);
  return fmaxf(__builtin_bit_cast(float, (unsigned)q),
               __builtin_bit_cast(float, (unsigned)(q >> 32)));
#else
  return fmaxf(x, __shfl_xor(x, 32, 64));
#endif
}
__device__ __forceinline__ float xhalf_add(float x) {
#if __has_builtin(__builtin_amdgcn_permlane32_swap)
  auto r = __builtin_amdgcn_permlane32_swap(
      __builtin_bit_cast(unsigned, x), __builtin_bit_cast(unsigned, x), false, false);
  unsigned long long q = __builtin_bit_cast(unsigned long long, r);
  return __builtin_bit_cast(float, (unsigned)q) +
         __builtin_bit_cast(float, (unsigned)(q >> 32));
#else
  return x + __shfl_xor(x, 32, 64);
#endif
}

// P C-layout -> B-operand mix across lane halves, on the VALU (no LDS pipe):
// want lanes<32: {A0_L, A0_{L+32}}, lanes>=32: {A1_{L-32}, A1_L}.
// v_permlane32_swap(a,b): a' = {a.lo, b.lo}, b' = {a.hi, b.hi} (per 32-lane half).
__device__ __forceinline__ f16x8 pfrag_mix(f16x4 A0, f16x4 A1) {
#if __has_builtin(__builtin_amdgcn_permlane32_swap)
  union { f16x4 v; unsigned u[2]; } a, b;
  a.v = A0;
  b.v = A1;
  auto r0 = __builtin_amdgcn_permlane32_swap(a.u[0], b.u[0], false, false);
  auto r1 = __builtin_amdgcn_permlane32_swap(a.u[1], b.u[1], false, false);
  unsigned long long q0 = __builtin_bit_cast(unsigned long long, r0);
  unsigned long long q1 = __builtin_bit_cast(unsigned long long, r1);
  union { unsigned u[4]; f16x8 v; } out;
  out.u[0] = (unsigned)q0;
  out.u[1] = (unsigned)q1;
  out.u[2] = (unsigned)(q0 >> 32);
  out.u[3] = (unsigned)(q1 >> 32);
  return out.v;
#else
  int h = (threadIdx.x & 63) >> 5;
  QW snd;
  snd.v = h ? A0 : A1;
  QW rcv;
  rcv.q = __shfl_xor(snd.q, 32, 64);
  return h ? cat8(rcv.v, A1) : cat8(A0, rcv.v);
#endif
}

// async global->LDS 16B per lane: LDS dest = uniform base + lane*16
__device__ __forceinline__ void gload_lds16(const void* g, void* l) {
  __builtin_amdgcn_global_load_lds(
      (const __attribute__((address_space(1))) unsigned int*)g,
      (__attribute__((address_space(3))) unsigned int*)l, 16, 0, 0);
}

// Packed layouts:
//  theta (8B granule): off8  = ((q>>5)*(CI/4) + ci4)*32 + (q&31);  f16 = off8*4
//  phi  (16B granule): off16 = ((key>>5)*(CI/8) + ci8)*32 + (key&31); f16 = off16*8
//  gP   (16B granule): off16 = ((ci>>5)*(HW/8) + key8)*32 + (ci&31); f16 = off16*8

// ---------------- K0: x transpose -> xP packed  (+ 64 blocks also pack weights) --------
__global__ __launch_bounds__(256) void k0_prep(
    const float* __restrict__ x, _Float16* __restrict__ xP,
    const float* __restrict__ tw, const float* __restrict__ pw,
    const float* __restrict__ gw, const float* __restrict__ ow,
    _Float16* __restrict__ w16) {
  __shared__ _Float16 Lt[64 * 68];  // pad 68: 8B-aligned f16x4 rows
  int t = threadIdx.x;
  int sp0 = blockIdx.x * 64;
  int ch0 = blockIdx.y * 64;
  int b = blockIdx.z;
  const float* xb = x + (size_t)b * C_ * HW_;
#pragma unroll
  for (int i = 0; i < 4; ++i) {
    int ch = i * 16 + (t >> 4);
    int spg = (t & 15) * 4;
    f32x4 v = *(const f32x4*)&xb[(size_t)(ch0 + ch) * HW_ + sp0 + spg];
    f16x4 hv;
#pragma unroll
    for (int j = 0; j < 4; ++j) hv[j] = (_Float16)v[j];
    *(f16x4*)&Lt[ch * 68 + spg] = hv;
  }
  __syncthreads();
  _Float16* xPb = xP + (size_t)b * HW_ * C_;
  int l31 = t & 31;
  int c8 = t >> 5;  // 0..7
#pragma unroll
  for (int sph = 0; sph < 2; ++sph) {
    int spl = sph * 32 + l31;
    f16x8 v;
#pragma unroll
    for (int i = 0; i < 8; ++i) v[i] = Lt[(c8 * 8 + i) * 68 + spl];
    int sp = sp0 + spl;
    size_t off16 = ((size_t)(sp >> 5) * (C_ / 8) + (ch0 / 8 + c8)) * 32 + (sp & 31);
    *(f16x8*)&xPb[off16 * 8] = v;
  }
  // weight packing piggyback on 64 blocks (theta scaled by log2e)
  if (blockIdx.y == 0 && blockIdx.z == 0) {
    int g = blockIdx.x * 256 + t;  // 16384 chunks of 16B
    int ti = g >> 12;
    int local = g & 4095;
    const float* src = (ti == 0) ? tw : (ti == 1) ? pw : (ti == 2) ? gw : ow;
    float scl = (ti == 0) ? LOG2E : 1.f;
    if (ti < 3) {
      int r31 = local & 31, k8 = (local >> 5) & 31, rblk = local >> 10;
      src += (size_t)(rblk * 32 + r31) * 256 + k8 * 8;
    } else {
      int r31 = local & 31, k8 = (local >> 5) & 15, rblk = local >> 9;
      src += (size_t)(rblk * 32 + r31) * 128 + k8 * 8;
    }
    f32x4 a = *(const f32x4*)src;
    f32x4 c = *(const f32x4*)(src + 4);
    f16x8 hv;
#pragma unroll
    for (int j = 0; j < 4; ++j) {
      hv[j] = (_Float16)(a[j] * scl);
      hv[j + 4] = (_Float16)(c[j] * scl);
    }
    *(f16x8*)&w16[(size_t)ti * 32768 + (size_t)local * 8] = hv;
  }
}

// ---------------- K1: projections. theta: 8B granules; phi/g: 16B granules. ----
__global__ __launch_bounds__(256, 3) void k1_proj(
    const _Float16* __restrict__ xP, const _Float16* __restrict__ w16,
    const float* __restrict__ tb, const float* __restrict__ pb,
    const float* __restrict__ gb, _Float16* __restrict__ thetaP,
    _Float16* __restrict__ phiP, _Float16* __restrict__ gP) {
  int p = blockIdx.y;
  int b = blockIdx.z;
  int sp0 = blockIdx.x * 64;
  int tid = threadIdx.x;
  int w = tid >> 6;
  int lane = tid & 63;
  int l31 = lane & 31;
  int h = lane >> 5;
  const _Float16* xPb = xP + (size_t)b * HW_ * C_;
  f32x16 acc[2];
#pragma unroll
  for (int i = 0; i < 2; ++i)
#pragma unroll
    for (int j = 0; j < 16; ++j) acc[i][j] = 0.f;

  if (p < 2) {
    int wsp = w & 1, wci = w >> 1;
    const _Float16* W = w16 + (size_t)p * 32768;
#pragma unroll
    for (int ks = 0; ks < 16; ++ks) {
      int k8 = ks * 2 + h;
      f16x8 bf = *(const f16x8*)&xPb[((((sp0 >> 5) + wsp) * 32 + k8) * 32 + l31) * 8];
#pragma unroll
      for (int mt = 0; mt < 2; ++mt) {
        f16x8 af = *(const f16x8*)&W[((((wci * 2 + mt) * 32) + k8) * 32 + l31) * 8];
        acc[mt] = mfma16(af, bf, acc[mt]);
      }
    }
    int sp = sp0 + wsp * 32 + l31;
    if (p == 0) {
      // theta -> 8B granule layout (unchanged; k2 loads Bq once per block)
      _Float16* out = thetaP + (size_t)b * HW_ * CI_;
#pragma unroll
      for (int mt = 0; mt < 2; ++mt)
#pragma unroll
        for (int g4 = 0; g4 < 4; ++g4) {
          int cb = (wci * 2 + mt) * 32 + g4 * 8 + h * 4;
          f32x4 bv = *(const f32x4*)&tb[cb];
          f16x4 res = pk4(acc[mt][g4 * 4 + 0] + bv[0] * LOG2E,
                          acc[mt][g4 * 4 + 1] + bv[1] * LOG2E,
                          acc[mt][g4 * 4 + 2] + bv[2] * LOG2E,
                          acc[mt][g4 * 4 + 3] + bv[3] * LOG2E);
          size_t off8 = ((size_t)(sp >> 5) * (CI_ / 4) + (cb >> 2)) * 32 + (sp & 31);
          *(f16x4*)&out[off8 * 4] = res;
        }
    } else {
      // phi -> 16B granule layout: combine the two lane-halves' 4-ci pieces
      _Float16* out = phiP + (size_t)b * HW_ * CI_;
#pragma unroll
      for (int mt = 0; mt < 2; ++mt)
#pragma unroll
        for (int g4 = 0; g4 < 4; ++g4) {
          int cb = (wci * 2 + mt) * 32 + g4 * 8 + h * 4;
          f32x4 bv = *(const f32x4*)&pb[cb];
          f16x4 res = pk4(acc[mt][g4 * 4 + 0] + bv[0], acc[mt][g4 * 4 + 1] + bv[1],
                          acc[mt][g4 * 4 + 2] + bv[2], acc[mt][g4 * 4 + 3] + bv[3]);
          QW snd;
          snd.v = res;
          QW rcv;
          rcv.q = __shfl_xor(snd.q, 32, 64);
          f16x8 gran = h ? cat8(rcv.v, res) : cat8(res, rcv.v);
          if (h == (g4 & 1)) {
            int cb8 = (wci * 2 + mt) * 4 + g4;
            size_t off16 = ((size_t)(sp >> 5) * (CI_ / 8) + cb8) * 32 + (sp & 31);
            *(f16x8*)&out[off16 * 8] = gran;
          }
        }
    }
  } else {
    int wci = w;  // 0..3
    const _Float16* W = w16 + 2 * 32768;
#pragma unroll
    for (int ks = 0; ks < 16; ++ks) {
      int k8 = ks * 2 + h;
      f16x8 bf = *(const f16x8*)&W[((wci * 32 + k8) * 32 + l31) * 8];
#pragma unroll
      for (int mt = 0; mt < 2; ++mt) {
        f16x8 af = *(const f16x8*)&xPb[((((sp0 >> 5) + mt) * 32 + k8) * 32 + l31) * 8];
        acc[mt] = mfma16(af, bf, acc[mt]);
      }
    }
    float bv = gb[wci * 32 + l31];
    // g -> 16B granule layout: combine the two lane-halves' 4-key pieces
    _Float16* out = gP + (size_t)b * CI_ * HW_;
#pragma unroll
    for (int mt = 0; mt < 2; ++mt)
#pragma unroll
      for (int g4 = 0; g4 < 4; ++g4) {
        f16x4 res = pk4(acc[mt][g4 * 4 + 0] + bv, acc[mt][g4 * 4 + 1] + bv,
                        acc[mt][g4 * 4 + 2] + bv, acc[mt][g4 * 4 + 3] + bv);
        QW snd;
        snd.v = res;
        QW rcv;
        rcv.q = __shfl_xor(snd.q, 32, 64);
        f16x8 gran = h ? cat8(rcv.v, res) : cat8(res, rcv.v);
        if (h == (g4 & 1)) {
          int key8 = (sp0 >> 3) + mt * 4 + g4;
          size_t off16 = ((size_t)wci * (HW_ / 8) + key8) * 32 + l31;
          *(f16x8*)&out[off16 * 8] = gran;
        }
      }
  }
}

// ---------------- K2: flash attention, KVBLK=32, (256,3), 3-buffer DMA staging.
//   Round-8 restructure: software-pipelined QK (sT cur / sN next) puts next tile's
//   8-MFMA chain in the SAME basic block as this tile's softmax -> compiler
//   interleaves MFMA and VALU (deterministic within-wave overlap). Softmax is
//   BRANCHLESS (always-rescale: alpha=1 exactly when max unchanged) so the whole
//   iter is one scheduling region. pfrag built with permlane32_swap (VALU, not
//   LDS pipe). Row-sum via VALU tree (ones-MFMA dropped: 16 AGPRs -> sN). ----
__global__ __launch_bounds__(256, 3) void k2_attn(
    const _Float16* __restrict__ thetaP, const _Float16* __restrict__ phiP,
    const _Float16* __restrict__ gP, _Float16* __restrict__ OpA,
    _Float16* __restrict__ OpB, float* __restrict__ ml) {
  // per buffer 16 KB: phi granules [0,4096) f16, g granules [4096,8192) f16
  __shared__ _Float16 lds[3][8192];
  int s = blockIdx.y;
  int b = blockIdx.z;
  int q0 = blockIdx.x * 128;
  int tid = threadIdx.x;
  int w = tid >> 6;
  int lane = tid & 63;
  int l31 = lane & 31;
  int h = lane >> 5;
  int qblk = (q0 >> 5) + w;
  const _Float16* thb = thetaP + (size_t)b * HW_ * CI_;
  const _Float16* phb = phiP + (size_t)b * HW_ * CI_;
  const _Float16* gvb = gP + (size_t)b * CI_ * HW_;

  f16x8 Bq[8];
#pragma unroll
  for (int ks = 0; ks < 8; ++ks) {
    f16x4 lo = *(const f16x4*)&thb[(((size_t)qblk * 32 + ks * 4 + h * 2) * 32 + l31) * 4];
    f16x4 hi = *(const f16x4*)&thb[(((size_t)qblk * 32 + ks * 4 + h * 2 + 1) * 32 + l31) * 4];
    Bq[ks] = cat8(lo, hi);
  }

  f32x16 o[4];
#pragma unroll
  for (int i = 0; i < 4; ++i)
#pragma unroll
    for (int j = 0; j < 16; ++j) o[i][j] = 0.f;
  float m_run = -1e30f, l_run = 0.f;

  // KS=6 split of the 128 key-tiles (32 keys each)
  int t0 = (s * 128) / 6;
  int t1 = ((s + 1) * 128) / 6;

  // rotating buffer pointers: read base (this lane's granule) + write base (wave chunks)
  const int lgran = (h * 32 + l31) * 8;
  const _Float16* Ra = &lds[0][lgran];
  const _Float16* Rb = &lds[1][lgran];
  const _Float16* Rc = &lds[2][lgran];
  _Float16* Wa = &lds[0][w * 2048];
  _Float16* Wb = &lds[1][w * 2048];
  _Float16* Wc = &lds[2][w * 2048];

  // per-wave running global srcs for its 4 staging chunks (waves 0,1: phi; 2,3: g)
  const _Float16 *src0, *src1, *src2, *src3;
  int stride;  // f16 per key-tile
  if (w < 2) {
    src0 = &phb[((size_t)t0 * 512 + (w * 4) * 64 + lane) * 8];
    src1 = src0 + 512;
    src2 = src0 + 1024;
    src3 = src0 + 1536;
    stride = 4096;
  } else {
    int j0 = (w - 2) * 4;
    src0 = &gvb[((size_t)(j0 >> 1) * 16384 + (size_t)t0 * 128 + lane) * 8];
    src1 = src0 + 512;
    src2 = src0 + 131072;  // (j0+2)>>1 step: +16384*8 f16
    src3 = src2 + 512;
    stride = 1024;
  }
  int tn = t0;  // tile the src pointers currently address
  auto stage4 = [&](_Float16* Wp) {
    gload_lds16(src0, Wp);
    gload_lds16(src1, Wp + 512);
    gload_lds16(src2, Wp + 1024);
    gload_lds16(src3, Wp + 1536);
    if (tn + 1 < t1) {  // freeze at last tile -> tail calls re-stage last tile (never read)
      src0 += stride; src1 += stride; src2 += stride; src3 += stride;
      ++tn;
    }
  };

  stage4(Wa);  // tile t0
  stage4(Wb);  // tile t0+1
  // prologue: buffer t0 ready (own 4 drained + barrier -> all waves' chunks landed)
  asm volatile("s_waitcnt vmcnt(4)" ::: "memory");
  __builtin_amdgcn_sched_barrier(0);
  __builtin_amdgcn_s_barrier();
  __builtin_amdgcn_sched_barrier(0);
  f32x16 sT;
#pragma unroll
  for (int j = 0; j < 16; ++j) sT[j] = 0.f;
#pragma unroll
  for (int ks = 0; ks < 8; ++ks) {
    f16x8 af = *(const f16x8*)(Ra + ks * 512);
    sT = mfma16(af, Bq[ks], sT);
  }

  for (int t = t0; t < t1; ++t) {
    // drain own next-tile loads (issued ~1 iter ago), then barrier -> buffer t+1
    // fully landed from all waves; buffer t landed since last iter.
    asm volatile("s_waitcnt vmcnt(0)" ::: "memory");
    __builtin_amdgcn_sched_barrier(0);
    __builtin_amdgcn_s_barrier();
    __builtin_amdgcn_sched_barrier(0);
    stage4(Wc);  // tile t+2 (or harmless dup of last tile)
    __builtin_amdgcn_s_setprio(1);
    // ---- QK^T for tile t+1 (reads Rb). On the last iter this reads the dup
    // tile and sN is discarded. Interleaves with softmax(sT) below. ----
    f32x16 sN;
#pragma unroll
    for (int j = 0; j < 16; ++j) sN[j] = 0.f;
#pragma unroll
    for (int ks = 0; ks < 8; ++ks) {
      f16x8 af = *(const f16x8*)(Rb + ks * 512);
      sN = mfma16(af, Bq[ks], sN);
    }
    // ---- branchless online softmax on sT (log2 domain, always-rescale) ----
    float a0 = fmax3(sT[0], sT[1], sT[2]);
    float a1 = fmax3(sT[3], sT[4], sT[5]);
    float a2 = fmax3(sT[6], sT[7], sT[8]);
    float a3 = fmax3(sT[9], sT[10], sT[11]);
    float a4 = fmax3(sT[12], sT[13], sT[14]);
    float b0 = fmax3(a0, a1, sT[15]);
    float b1 = fmax3(a2, a3, a4);
    float vmax = xhalf_max(fmaxf(b0, b1));
    float m_new = fmaxf(m_run, vmax);
    float alpha = exp2f(m_run - m_new);  // == 1.0 exactly when max unchanged
    m_run = m_new;
#pragma unroll
    for (int i = 0; i < 4; ++i)
#pragma unroll
      for (int j = 0; j < 16; ++j) o[i][j] *= alpha;
#pragma unroll
    for (int r = 0; r < 16; ++r) sT[r] = exp2f(sT[r] - m_new);
    float ps[8];
#pragma unroll
    for (int r = 0; r < 8; ++r) ps[r] = sT[r] + sT[r + 8];
#pragma unroll
    for (int st = 4; st > 0; st >>= 1)
#pragma unroll
      for (int r = 0; r < st; ++r) ps[r] += ps[r + st];
    l_run = l_run * alpha + xhalf_add(ps[0]);
    // ---- P: C-layout -> B-operand via permlane32_swap (VALU) ----
    f16x8 pfrag[2];
#pragma unroll
    for (int k2i = 0; k2i < 2; ++k2i) {
      int rb = k2i * 8;
      f16x4 A0 = pk4(sT[rb + 0], sT[rb + 1], sT[rb + 2], sT[rb + 3]);
      f16x4 A1 = pk4(sT[rb + 4], sT[rb + 5], sT[rb + 6], sT[rb + 7]);
      pfrag[k2i] = pfrag_mix(A0, A1);
    }
    // ---- PV: O^T += g (ci) x P^T (q), from Ra ----
#pragma unroll
    for (int kv = 0; kv < 2; ++kv) {
#pragma unroll
      for (int mt2 = 0; mt2 < 4; ++mt2) {
        f16x8 af = *(const f16x8*)(Ra + 4096 + mt2 * 1024 + kv * 512);
        o[mt2] = mfma16(af, pfrag[kv], o[mt2]);
      }
    }
    __builtin_amdgcn_s_setprio(0);
    // rotate buffers; promote next scores
    const _Float16* rt = Ra; Ra = Rb; Rb = Rc; Rc = rt;
    _Float16* wt = Wa; Wa = Wb; Wb = Wc; Wc = wt;
    sT = sN;
  }
  // drain leftover DMAs before LDS can be reallocated to another block
  asm volatile("s_waitcnt vmcnt(0)" ::: "memory");
  // ---- epilogue: normalized partial O in packed (row=q, k=ci, 8B) layout ----
  float inv = 1.f / l_run;
  int S = b * KS_ + s;
  _Float16* Op = (S < 16) ? (OpA + (size_t)S * ((size_t)HW_ * CI_))
                          : (OpB + (size_t)(S - 16) * ((size_t)HW_ * CI_));
#pragma unroll
  for (int mt2 = 0; mt2 < 4; ++mt2)
#pragma unroll
    for (int g4 = 0; g4 < 4; ++g4) {
      f16x4 res = pk4(o[mt2][g4 * 4 + 0] * inv, o[mt2][g4 * 4 + 1] * inv,
                      o[mt2][g4 * 4 + 2] * inv, o[mt2][g4 * 4 + 3] * inv);
      int ci4 = mt2 * 8 + g4 * 2 + h;
      size_t off8 = ((size_t)qblk * 32 + ci4) * 32 + l31;
      *(f16x4*)&Op[off8 * 4] = res;
    }
  if (h == 0) {
    int q = qblk * 32 + l31;
    *(float2*)&ml[((size_t)S * HW_ + q) * 2] = make_float2(m_run, l_run);
  }
}

// ---------------- K3: split-merge ONCE (LDS-shared) + out conv -> oc16 (f16). ----
__global__ __launch_bounds__(256, 3) void k3_outconv(
    const _Float16* __restrict__ OpA, const _Float16* __restrict__ OpB,
    const float* __restrict__ ml, const _Float16* __restrict__ wo,
    const float* __restrict__ ob, _Float16* __restrict__ oc16) {
  __shared__ _Float16 mrg[16 * 32 * 8];  // 8 KB merged B-fragments [k8][l31][8ci]
  int b = blockIdx.z;
  int qblk = blockIdx.x;  // 32 spatial rows per block
  int s0 = qblk * 32;
  int tid = threadIdx.x;
  int w = tid >> 6;
  int lane = tid & 63;
  int l31 = lane & 31;
  int h = lane >> 5;
  int sp = s0 + l31;
  const _Float16* Ops[KS_];
#pragma unroll
  for (int s = 0; s < KS_; ++s) {
    int S = b * KS_ + s;
    Ops[s] = (S < 16) ? (OpA + (size_t)S * ((size_t)HW_ * CI_))
                      : (OpB + (size_t)(S - 16) * ((size_t)HW_ * CI_));
  }
  // per-lane merge weights (lane's row sp is fixed)
  float m[KS_], l[KS_], M = -1e30f;
#pragma unroll
  for (int s = 0; s < KS_; ++s) {
    float2 v = *(const float2*)&ml[((size_t)(b * KS_ + s) * HW_ + sp) * 2];
    m[s] = v.x;
    l[s] = v.y;
    M = fmaxf(M, m[s]);
  }
  float den = 0.f, wgt[KS_];
#pragma unroll
  for (int s = 0; s < KS_; ++s) {
    wgt[s] = exp2f(m[s] - M) * l[s];
    den += wgt[s];
  }
  float inv = 1.f / den;
  f16x2 wh[KS_];
#pragma unroll
  for (int s = 0; s < KS_; ++s) {
    _Float16 ws = (_Float16)(wgt[s] * inv);
    wh[s][0] = ws;
    wh[s][1] = ws;
  }
  // ---- phase 1: wave w merges k8 in {w*4 .. w*4+3} (via kk x h), once total ----
#pragma unroll
  for (int kk = 0; kk < 2; ++kk) {
    int k8 = w * 4 + kk * 2 + h;
    F4 a0, a1;
    a0.h2[0] = f16x2{0, 0}; a0.h2[1] = f16x2{0, 0};
    a1.h2[0] = f16x2{0, 0}; a1.h2[1] = f16x2{0, 0};
    size_t base = ((size_t)qblk * 32 + k8 * 2) * 32 + l31;
#pragma unroll
    for (int s = 0; s < KS_; ++s) {
      F4 v0, v1;
      v0.v = *(const f16x4*)&Ops[s][base * 4];
      v1.v = *(const f16x4*)&Ops[s][(base + 32) * 4];
      a0.h2[0] += wh[s] * v0.h2[0];
      a0.h2[1] += wh[s] * v0.h2[1];
      a1.h2[0] += wh[s] * v1.h2[0];
      a1.h2[1] += wh[s] * v1.h2[1];
    }
    *(f16x8*)&mrg[(k8 * 32 + l31) * 8] = cat8(a0.v, a1.v);
  }
  __syncthreads();
  // ---- phase 2: wave w owns channels [w*64, w*64+64): 8 ks x 2 mt MFMAs ----
  f32x16 acc[2];
#pragma unroll
  for (int i = 0; i < 2; ++i)
#pragma unroll
    for (int j = 0; j < 16; ++j) acc[i][j] = 0.f;
#pragma unroll
  for (int ks = 0; ks < 8; ++ks) {
    int k8 = ks * 2 + h;
    f16x8 bf = *(const f16x8*)&mrg[(k8 * 32 + l31) * 8];
#pragma unroll
    for (int mt = 0; mt < 2; ++mt) {
      int rblk = w * 2 + mt;
      f16x8 af = *(const f16x8*)&wo[((rblk * 16 + k8) * 32 + l31) * 8];
      acc[mt] = mfma16(af, bf, acc[mt]);
    }
  }
#pragma unroll
  for (int mt = 0; mt < 2; ++mt)
#pragma unroll
    for (int r = 0; r < 16; ++r) {
      int c = (w * 2 + mt) * 32 + (r & 3) + 8 * (r >> 2) + 4 * h;
      oc16[((size_t)(b * C_ + c)) * HW_ + sp] = (_Float16)(acc[mt][r] + ob[c]);
    }
}

// ---------------- K4: fused BN stats + BN + ReLU + residual, one block/channel. ----
__global__ __launch_bounds__(1024) void k4_bnfused(
    const _Float16* __restrict__ oc16, const float* __restrict__ x,
    const float* __restrict__ gamma, const float* __restrict__ beta,
    float* __restrict__ out) {
  int c = blockIdx.x;
  int t = threadIdx.x;  // 0..1023: 4 f16 per batch image
  f16x4 vv[B_];
  float s = 0.f, s2 = 0.f;
#pragma unroll
  for (int b = 0; b < B_; ++b) {
    vv[b] = *(const f16x4*)&oc16[((size_t)(b * C_ + c)) * HW_ + t * 4];
#pragma unroll
    for (int j = 0; j < 4; ++j) {
      float f = (float)vv[b][j];
      s += f;
      s2 += f * f;
    }
  }
#pragma unroll
  for (int mm = 1; mm < 64; mm <<= 1) {
    s += __shfl_xor(s, mm, 64);
    s2 += __shfl_xor(s2, mm, 64);
  }
  __shared__ float ls[32];
  __shared__ float mv[2];
  int w = t >> 6, lane = t & 63;
  if (lane == 0) {
    ls[w] = s;
    ls[16 + w] = s2;
  }
  __syncthreads();
  if (t == 0) {
    float a = 0.f, bb = 0.f;
#pragma unroll
    for (int i = 0; i < 16; ++i) {
      a += ls[i];
      bb += ls[16 + i];
    }
    float mean = a * (1.f / 16384.f);
    mv[0] = mean;
    mv[1] = bb * (1.f / 16384.f) - mean * mean;
  }
  __syncthreads();
  float mean = mv[0];
  float sc = gamma[c] * rsqrtf(mv[1] + 1e-5f);
  float bt = beta[c];
#pragma unroll
  for (int b = 0; b < B_; ++b) {
    size_t base = ((size_t)(b * C_ + c)) * HW_ + t * 4;
    f32x4 xv = *(const f32x4*)&x[base];
    f32x4 r;
#pragma unroll
    for (int j = 0; j < 4; ++j) {
      float y = ((float)vv[b][j] - mean) * sc + bt;
      y = fmaxf(y, 0.f);
      r[j] = y + xv[j];
    }
    *(f32x4*)&out[base] = r;
  }
}

extern "C" void kernel_launch(void* const* d_in, const int* in_sizes, int n_in,
                              void* d_out, int out_size, void* d_ws,
                              size_t ws_size, hipStream_t stream) {
  const float* x = (const float*)d_in[0];
  const float* g_w = (const float*)d_in[1];
  const float* g_b = (const float*)d_in[2];
  const float* th_w = (const float*)d_in[3];
  const float* th_b = (const float*)d_in[4];
  const float* ph_w = (const float*)d_in[5];
  const float* ph_b = (const float*)d_in[6];
  const float* o_w = (const float*)d_in[7];
  const float* o_b = (const float*)d_in[8];
  const float* gam = (const float*)d_in[9];
  const float* bet = (const float*)d_in[10];

  // Workspace map:
  //  [0,8M)    xP (k0->k1), then Opart chunks 16..23 (k2->k3)
  //  [8M,16M)  thetaP(8-12M)/phiP(12-16M) (k1->k2), then oc16 (k3->k4)
  //  [16M,20M) gP (k1->k2)
  //  [20M,..)  ml (768KB)
  //  [24M,..)  w16 (256KB, k0->k3)
  char* ws = (char*)d_ws;
  _Float16* xP = (_Float16*)ws;
  _Float16* OpB = (_Float16*)ws;                  // 8 MB: Opart chunks 16..23
  _Float16* oc16 = (_Float16*)(ws + 8388608);     // 8 MB f16 out-conv result
  _Float16* thetaP = (_Float16*)(ws + 8388608);   // 4 MB
  _Float16* phiP = (_Float16*)(ws + 12582912);    // 4 MB
  _Float16* gP = (_Float16*)(ws + 16777216);      // 4 MB
  float* ml = (float*)(ws + 20971520);            // 768 KB (24 splits)
  _Float16* w16 = (_Float16*)(ws + 25165824);     // 256 KB
  _Float16* OpA = (_Float16*)d_out;               // 16 MB: Opart chunks 0..15

  k0_prep<<<dim3(64, 4, 4), 256, 0, stream>>>(x, xP, th_w, ph_w, g_w, o_w, w16);
  k1_proj<<<dim3(64, 3, 4), 256, 0, stream>>>(xP, w16, th_b, ph_b, g_b, thetaP,
                                              phiP, gP);
  k2_attn<<<dim3(32, KS_, 4), 256, 0, stream>>>(thetaP, phiP, gP, OpA, OpB, ml);
  k3_outconv<<<dim3(128, 1, 4), 256, 0, stream>>>(OpA, OpB, ml, w16 + 3 * 32768,
                                                  o_b, oc16);
  k4_bnfused<<<256, 1024, 0, stream>>>(oc16, x, gam, bet, (float*)d_out);
}

// Round 9
// 161.154 us; speedup vs baseline: 1.0404x; 1.0404x over previous
//
#include <hip/hip_runtime.h>

#define B_ 4
#define C_ 256
#define CI_ 128
#define HW_ 4096
#define KS_ 6
#define LOG2E 1.44269504f
#define RESCALE_THR 8.f

typedef _Float16 f16x8 __attribute__((ext_vector_type(8)));
typedef _Float16 f16x4 __attribute__((ext_vector_type(4)));
typedef _Float16 f16x2 __attribute__((ext_vector_type(2)));
typedef __fp16 fp16x2 __attribute__((ext_vector_type(2)));
typedef float f32x16 __attribute__((ext_vector_type(16)));
typedef float f32x4 __attribute__((ext_vector_type(4)));

__device__ __forceinline__ f32x16 mfma16(f16x8 a, f16x8 b, f32x16 c) {
  return __builtin_amdgcn_mfma_f32_32x32x16_f16(a, b, c, 0, 0, 0);
}
__device__ __forceinline__ f16x8 cat8(f16x4 a, f16x4 b) {
  return __builtin_shufflevector(a, b, 0, 1, 2, 3, 4, 5, 6, 7);
}
__device__ __forceinline__ f16x4 pk4(float a, float b, float c, float d) {
  union { fp16x2 p[2]; f16x4 v; } u;
  u.p[0] = __builtin_amdgcn_cvt_pkrtz(a, b);
  u.p[1] = __builtin_amdgcn_cvt_pkrtz(c, d);
  return u.v;
}
__device__ __forceinline__ float fmax3(float a, float b, float c) {
  return fmaxf(fmaxf(a, b), c);  // clang fuses to v_max3_f32
}
union QW { f16x4 v; long long q; };
union F4 { f16x4 v; f16x2 h2[2]; };

// Cross-half (lane ^ 32) reduce via permlane32_swap(x,x).
__device__ __forceinline__ float xhalf_max(float x) {
#if __has_builtin(__builtin_amdgcn_permlane32_swap)
  auto r = __builtin_amdgcn_permlane32_swap(
      __builtin_bit_cast(unsigned, x), __builtin_bit_cast(unsigned, x), false, false);
  unsigned long long q = __builtin_bit_cast(unsigned long long, r);
  return fmaxf(__builtin_bit_cast(float, (unsigned)q),
               __builtin_bit_cast(float, (unsigned)(q >> 32)));
#else
  return fmaxf(x, __shfl_xor(x, 32, 64));
#endif
}

// async global->LDS 16B per lane: LDS dest = uniform base + lane*16
__device__ __forceinline__ void gload_lds16(const void* g, void* l) {
  __builtin_amdgcn_global_load_lds(
      (const __attribute__((address_space(1))) unsigned int*)g,
      (__attribute__((address_space(3))) unsigned int*)l, 16, 0, 0);
}

// Packed layouts:
//  theta (8B granule): off8  = ((q>>5)*(CI/4) + ci4)*32 + (q&31);  f16 = off8*4
//  phi  (16B granule): off16 = ((key>>5)*(CI/8) + ci8)*32 + (key&31); f16 = off16*8
//  gP   (16B granule): off16 = ((ci>>5)*(HW/8) + key8)*32 + (ci&31); f16 = off16*8

// ---------------- K0w: weight packing only (theta scaled by log2e) ----------------
__global__ __launch_bounds__(256) void k0w_pack(
    const float* __restrict__ tw, const float* __restrict__ pw,
    const float* __restrict__ gw, const float* __restrict__ ow,
    _Float16* __restrict__ w16) {
  int g = blockIdx.x * 256 + threadIdx.x;  // 64 blocks -> 16384 chunks of 16B
  int ti = g >> 12;
  int local = g & 4095;
  const float* src = (ti == 0) ? tw : (ti == 1) ? pw : (ti == 2) ? gw : ow;
  float scl = (ti == 0) ? LOG2E : 1.f;
  if (ti < 3) {
    int r31 = local & 31, k8 = (local >> 5) & 31, rblk = local >> 10;
    src += (size_t)(rblk * 32 + r31) * 256 + k8 * 8;
  } else {
    int r31 = local & 31, k8 = (local >> 5) & 15, rblk = local >> 9;
    src += (size_t)(rblk * 32 + r31) * 128 + k8 * 8;
  }
  f32x4 a = *(const f32x4*)src;
  f32x4 c = *(const f32x4*)(src + 4);
  f16x8 hv;
#pragma unroll
  for (int j = 0; j < 4; ++j) {
    hv[j] = (_Float16)(a[j] * scl);
    hv[j + 4] = (_Float16)(c[j] * scl);
  }
  *(f16x8*)&w16[(size_t)ti * 32768 + (size_t)local * 8] = hv;
}

// ---------------- K01: fused x-transpose (to LDS granules) + all 3 projections.
//   Block = 64 spatial x 256 ch, 512 threads (8 waves), grid 64x4 = 1 block/CU.
//   Kills the xP global round-trip (8 MB write + 24 MB read) and one launch.
//   Phase A/B: stage x -> Lt -> xPl granules (two 128-ch chunks, 50 KB LDS).
//   Phase C: EXACT k1 compute bodies, bf/af read from xPl instead of global xP.
//   Waves 0-3: theta; waves 4-7: phi; then all 8 waves: g (one mt each). ----
__global__ __launch_bounds__(512, 2) void k01_fused(
    const float* __restrict__ x, const _Float16* __restrict__ w16,
    const float* __restrict__ tb, const float* __restrict__ pb,
    const float* __restrict__ gb, _Float16* __restrict__ thetaP,
    _Float16* __restrict__ phiP, _Float16* __restrict__ gP) {
  __shared__ _Float16 Lt[128 * 68];  // 17.4 KB: 128 ch x 64 sp (pad 68)
  __shared__ _Float16 xPl[16384];    // 32 KB: 64 sp x 256 ch in granule layout
  int b = blockIdx.z;
  int sp0 = blockIdx.x * 64;
  int t = threadIdx.x;  // 0..511
  const float* xb = x + (size_t)b * C_ * HW_;
  // ---- phases A/B: two 128-channel chunks ----
  for (int cb = 0; cb < 2; ++cb) {
    // A: load 128 ch x 64 sp, f32->f16
#pragma unroll
    for (int i = 0; i < 4; ++i) {
      int r = i * 32 + (t >> 4);  // 0..127
      int spg = (t & 15) * 4;
      f32x4 v = *(const f32x4*)&xb[(size_t)(cb * 128 + r) * HW_ + sp0 + spg];
      f16x4 hv;
#pragma unroll
      for (int j = 0; j < 4; ++j) hv[j] = (_Float16)v[j];
      *(f16x4*)&Lt[r * 68 + spg] = hv;
    }
    __syncthreads();
    // B: pack into 16B granules: off16 = (sph*(C/8) + ch8)*32 + l31
    {
      int l31 = t & 31;
      int c8l = t >> 5;  // 0..15
#pragma unroll
      for (int sph = 0; sph < 2; ++sph) {
        int spl = sph * 32 + l31;
        f16x8 v;
#pragma unroll
        for (int i = 0; i < 8; ++i) v[i] = Lt[(c8l * 8 + i) * 68 + spl];
        int ch8 = cb * 16 + c8l;
        *(f16x8*)&xPl[((sph * 32 + ch8) * 32 + l31) * 8] = v;
      }
    }
    __syncthreads();
  }
  // ---- phase C ----
  int w = t >> 6;  // 0..7
  int lane = t & 63;
  int l31 = lane & 31;
  int h = lane >> 5;
  // p in {0,1}: waves 0-3 -> theta, waves 4-7 -> phi (exact k1 p<2 body)
  {
    int p = w >> 2;
    int w4 = w & 3;
    int wsp = w4 & 1, wci = w4 >> 1;
    const _Float16* W = w16 + (size_t)p * 32768;
    f32x16 acc[2];
#pragma unroll
    for (int i = 0; i < 2; ++i)
#pragma unroll
      for (int j = 0; j < 16; ++j) acc[i][j] = 0.f;
#pragma unroll
    for (int ks = 0; ks < 16; ++ks) {
      int k8 = ks * 2 + h;
      f16x8 bf = *(const f16x8*)&xPl[((wsp * 32 + k8) * 32 + l31) * 8];
#pragma unroll
      for (int mt = 0; mt < 2; ++mt) {
        f16x8 af = *(const f16x8*)&W[((((wci * 2 + mt) * 32) + k8) * 32 + l31) * 8];
        acc[mt] = mfma16(af, bf, acc[mt]);
      }
    }
    int sp = sp0 + wsp * 32 + l31;
    if (p == 0) {
      // theta -> 8B granule layout
      _Float16* out = thetaP + (size_t)b * HW_ * CI_;
#pragma unroll
      for (int mt = 0; mt < 2; ++mt)
#pragma unroll
        for (int g4 = 0; g4 < 4; ++g4) {
          int cb2 = (wci * 2 + mt) * 32 + g4 * 8 + h * 4;
          f32x4 bv = *(const f32x4*)&tb[cb2];
          f16x4 res = pk4(acc[mt][g4 * 4 + 0] + bv[0] * LOG2E,
                          acc[mt][g4 * 4 + 1] + bv[1] * LOG2E,
                          acc[mt][g4 * 4 + 2] + bv[2] * LOG2E,
                          acc[mt][g4 * 4 + 3] + bv[3] * LOG2E);
          size_t off8 = ((size_t)(sp >> 5) * (CI_ / 4) + (cb2 >> 2)) * 32 + (sp & 31);
          *(f16x4*)&out[off8 * 4] = res;
        }
    } else {
      // phi -> 16B granule layout: combine the two lane-halves' 4-ci pieces
      _Float16* out = phiP + (size_t)b * HW_ * CI_;
#pragma unroll
      for (int mt = 0; mt < 2; ++mt)
#pragma unroll
        for (int g4 = 0; g4 < 4; ++g4) {
          int cb2 = (wci * 2 + mt) * 32 + g4 * 8 + h * 4;
          f32x4 bv = *(const f32x4*)&pb[cb2];
          f16x4 res = pk4(acc[mt][g4 * 4 + 0] + bv[0], acc[mt][g4 * 4 + 1] + bv[1],
                          acc[mt][g4 * 4 + 2] + bv[2], acc[mt][g4 * 4 + 3] + bv[3]);
          QW snd;
          snd.v = res;
          QW rcv;
          rcv.q = __shfl_xor(snd.q, 32, 64);
          f16x8 gran = h ? cat8(rcv.v, res) : cat8(res, rcv.v);
          if (h == (g4 & 1)) {
            int cb8 = (wci * 2 + mt) * 4 + g4;
            size_t off16 = ((size_t)(sp >> 5) * (CI_ / 8) + cb8) * 32 + (sp & 31);
            *(f16x8*)&out[off16 * 8] = gran;
          }
        }
    }
  }
  // p=2: g projection, all 8 waves: wci = w&3, mt = w>>2 (exact k1 p=2 body, split)
  {
    int wci = w & 3;
    int mt = w >> 2;
    const _Float16* W = w16 + 2 * 32768;
    f32x16 acc;
#pragma unroll
    for (int j = 0; j < 16; ++j) acc[j] = 0.f;
#pragma unroll
    for (int ks = 0; ks < 16; ++ks) {
      int k8 = ks * 2 + h;
      f16x8 bf = *(const f16x8*)&W[((wci * 32 + k8) * 32 + l31) * 8];
      f16x8 af = *(const f16x8*)&xPl[((mt * 32 + k8) * 32 + l31) * 8];
      acc = mfma16(af, bf, acc);
    }
    float bv = gb[wci * 32 + l31];
    _Float16* out = gP + (size_t)b * CI_ * HW_;
#pragma unroll
    for (int g4 = 0; g4 < 4; ++g4) {
      f16x4 res = pk4(acc[g4 * 4 + 0] + bv, acc[g4 * 4 + 1] + bv,
                      acc[g4 * 4 + 2] + bv, acc[g4 * 4 + 3] + bv);
      QW snd;
      snd.v = res;
      QW rcv;
      rcv.q = __shfl_xor(snd.q, 32, 64);
      f16x8 gran = h ? cat8(rcv.v, res) : cat8(res, rcv.v);
      if (h == (g4 & 1)) {
        int key8 = (sp0 >> 3) + mt * 4 + g4;
        size_t off16 = ((size_t)wci * (HW_ / 8) + key8) * 32 + l31;
        *(f16x8*)&out[off16 * 8] = gran;
      }
    }
  }
}

// ---------------- K2: flash attention (r7 state: best 57.0 us, zero spill).
//   KVBLK=32, (256,3), 3-buffer counted-vmcnt DMA pipeline, ones-MFMA row-sum,
//   v_max3 tree, defer-max rescale. ----
__global__ __launch_bounds__(256, 3) void k2_attn(
    const _Float16* __restrict__ thetaP, const _Float16* __restrict__ phiP,
    const _Float16* __restrict__ gP, _Float16* __restrict__ OpA,
    _Float16* __restrict__ OpB, float* __restrict__ ml) {
  // per buffer 16 KB: phi granules [0,4096) f16, g granules [4096,8192) f16
  __shared__ _Float16 lds[3][8192];
  int s = blockIdx.y;
  int b = blockIdx.z;
  int q0 = blockIdx.x * 128;
  int tid = threadIdx.x;
  int w = tid >> 6;
  int lane = tid & 63;
  int l31 = lane & 31;
  int h = lane >> 5;
  int qblk = (q0 >> 5) + w;
  const _Float16* thb = thetaP + (size_t)b * HW_ * CI_;
  const _Float16* phb = phiP + (size_t)b * HW_ * CI_;
  const _Float16* gvb = gP + (size_t)b * CI_ * HW_;

  f16x8 Bq[8];
#pragma unroll
  for (int ks = 0; ks < 8; ++ks) {
    f16x4 lo = *(const f16x4*)&thb[(((size_t)qblk * 32 + ks * 4 + h * 2) * 32 + l31) * 4];
    f16x4 hi = *(const f16x4*)&thb[(((size_t)qblk * 32 + ks * 4 + h * 2 + 1) * 32 + l31) * 4];
    Bq[ks] = cat8(lo, hi);
  }

  f32x16 o[4];
#pragma unroll
  for (int i = 0; i < 4; ++i)
#pragma unroll
    for (int j = 0; j < 16; ++j) o[i][j] = 0.f;
  f32x16 ol;  // row-sum accumulator: ol[0] = l for q = lane&31
#pragma unroll
  for (int j = 0; j < 16; ++j) ol[j] = 0.f;
  float m_run = -1e30f;
  f16x8 one8;
#pragma unroll
  for (int j = 0; j < 8; ++j) one8[j] = (_Float16)1.f;

  // KS=6 split of the 128 key-tiles (32 keys each)
  int t0 = (s * 128) / 6;
  int t1 = ((s + 1) * 128) / 6;

  // rotating buffer pointers: read base (this lane's granule) + write base (wave chunks)
  const int lgran = (h * 32 + l31) * 8;
  const _Float16* Ra = &lds[0][lgran];
  const _Float16* Rb = &lds[1][lgran];
  const _Float16* Rc = &lds[2][lgran];
  _Float16* Wa = &lds[0][w * 2048];
  _Float16* Wb = &lds[1][w * 2048];
  _Float16* Wc = &lds[2][w * 2048];

  // per-wave running global srcs for its 4 staging chunks (waves 0,1: phi; 2,3: g)
  const _Float16 *src0, *src1, *src2, *src3;
  int stride;  // f16 per key-tile
  if (w < 2) {
    src0 = &phb[((size_t)t0 * 512 + (w * 4) * 64 + lane) * 8];
    src1 = src0 + 512;
    src2 = src0 + 1024;
    src3 = src0 + 1536;
    stride = 4096;
  } else {
    int j0 = (w - 2) * 4;
    src0 = &gvb[((size_t)(j0 >> 1) * 16384 + (size_t)t0 * 128 + lane) * 8];
    src1 = src0 + 512;
    src2 = src0 + 131072;  // (j0+2)>>1 step: +16384*8 f16
    src3 = src2 + 512;
    stride = 1024;
  }
  int tn = t0;  // tile the src pointers currently address
  auto stage4 = [&](_Float16* Wp) {
    gload_lds16(src0, Wp);
    gload_lds16(src1, Wp + 512);
    gload_lds16(src2, Wp + 1024);
    gload_lds16(src3, Wp + 1536);
    if (tn + 1 < t1) {  // freeze at last tile -> tail calls = dummy re-stage
      src0 += stride; src1 += stride; src2 += stride; src3 += stride;
      ++tn;
    }
  };

  stage4(Wa);  // tile t0
  stage4(Wb);  // tile t0+1

  for (int t = t0; t < t1; ++t) {
    // counted wait: drain this tile's 4 loads; next tiles' 8 stay in flight
    asm volatile("s_waitcnt vmcnt(4)" ::: "memory");
    __builtin_amdgcn_sched_barrier(0);
    __builtin_amdgcn_s_barrier();
    __builtin_amdgcn_sched_barrier(0);
    // issue tile t+2's DMA into the buffer freed by tile t-1 (barrier-gated)
    stage4(Wc);
    // ---- QK^T (S^T): A = phi rows (key), B = theta (q); base+imm ds_read_b128 ----
    f32x16 sT;
#pragma unroll
    for (int j = 0; j < 16; ++j) sT[j] = 0.f;
    __builtin_amdgcn_s_setprio(1);
#pragma unroll
    for (int ks = 0; ks < 8; ++ks) {
      f16x8 af = *(const f16x8*)(Ra + ks * 512);
      sT = mfma16(af, Bq[ks], sT);
    }
    __builtin_amdgcn_s_setprio(0);
    // ---- online softmax, log2 domain; v_max3 tree + defer-max rescale ----
    float a0 = fmax3(sT[0], sT[1], sT[2]);
    float a1 = fmax3(sT[3], sT[4], sT[5]);
    float a2 = fmax3(sT[6], sT[7], sT[8]);
    float a3 = fmax3(sT[9], sT[10], sT[11]);
    float a4 = fmax3(sT[12], sT[13], sT[14]);
    float b0 = fmax3(a0, a1, sT[15]);
    float b1 = fmax3(a2, a3, a4);
    float vmax = xhalf_max(fmaxf(b0, b1));
    if (!__all(vmax <= m_run + RESCALE_THR)) {
      float m_new = fmaxf(m_run, vmax);
      float alpha = exp2f(m_run - m_new);
#pragma unroll
      for (int i = 0; i < 4; ++i)
#pragma unroll
        for (int j = 0; j < 16; ++j) o[i][j] *= alpha;
      ol[0] *= alpha;  // only ol[0] is ever read
      m_run = m_new;
    }
#pragma unroll
    for (int r = 0; r < 16; ++r) sT[r] = exp2f(sT[r] - m_run);
    // ---- P: C-layout -> B-operand via cross-half shuffle ----
    f16x8 pfrag[2];
#pragma unroll
    for (int k2i = 0; k2i < 2; ++k2i) {
      int rb = k2i * 8;
      f16x4 A0 = pk4(sT[rb + 0], sT[rb + 1], sT[rb + 2], sT[rb + 3]);
      f16x4 A1 = pk4(sT[rb + 4], sT[rb + 5], sT[rb + 6], sT[rb + 7]);
      QW snd;
      snd.v = h ? A0 : A1;  // h=0 sends rows 8..11, h=1 sends rows 4..7
      QW rcv;
      rcv.q = __shfl_xor(snd.q, 32, 64);
      pfrag[k2i] = h ? cat8(rcv.v, A1) : cat8(A0, rcv.v);
    }
    // ---- PV: O^T += g (ci) x P^T (q); plus ones-row MFMA accumulates l ----
    __builtin_amdgcn_s_setprio(1);
#pragma unroll
    for (int kv = 0; kv < 2; ++kv) {
#pragma unroll
      for (int mt2 = 0; mt2 < 4; ++mt2) {
        f16x8 af = *(const f16x8*)(Ra + 4096 + mt2 * 1024 + kv * 512);
        o[mt2] = mfma16(af, pfrag[kv], o[mt2]);
      }
      ol = mfma16(one8, pfrag[kv], ol);
    }
    __builtin_amdgcn_s_setprio(0);
    // rotate buffers (no end-of-tile barrier: next iter's barrier gates reuse)
    const _Float16* rt = Ra; Ra = Rb; Rb = Rc; Rc = rt;
    _Float16* wt = Wa; Wa = Wb; Wb = Wc; Wc = wt;
  }
  // drain leftover dummy DMAs before LDS can be reallocated to another block
  asm volatile("s_waitcnt vmcnt(0)" ::: "memory");
  // ---- epilogue: normalized partial O in packed (row=q, k=ci, 8B) layout ----
  float l_run = ol[0];
  float inv = 1.f / l_run;
  int S = b * KS_ + s;
  _Float16* Op = (S < 16) ? (OpA + (size_t)S * ((size_t)HW_ * CI_))
                          : (OpB + (size_t)(S - 16) * ((size_t)HW_ * CI_));
#pragma unroll
  for (int mt2 = 0; mt2 < 4; ++mt2)
#pragma unroll
    for (int g4 = 0; g4 < 4; ++g4) {
      f16x4 res = pk4(o[mt2][g4 * 4 + 0] * inv, o[mt2][g4 * 4 + 1] * inv,
                      o[mt2][g4 * 4 + 2] * inv, o[mt2][g4 * 4 + 3] * inv);
      int ci4 = mt2 * 8 + g4 * 2 + h;
      size_t off8 = ((size_t)qblk * 32 + ci4) * 32 + l31;
      *(f16x4*)&Op[off8 * 4] = res;
    }
  if (h == 0) {
    int q = qblk * 32 + l31;
    *(float2*)&ml[((size_t)S * HW_ + q) * 2] = make_float2(m_run, l_run);
  }
}

// ---------------- K3: split-merge ONCE (LDS-shared) + out conv -> oc16 (f16). ----
__global__ __launch_bounds__(256, 3) void k3_outconv(
    const _Float16* __restrict__ OpA, const _Float16* __restrict__ OpB,
    const float* __restrict__ ml, const _Float16* __restrict__ wo,
    const float* __restrict__ ob, _Float16* __restrict__ oc16) {
  __shared__ _Float16 mrg[16 * 32 * 8];  // 8 KB merged B-fragments [k8][l31][8ci]
  int b = blockIdx.z;
  int qblk = blockIdx.x;  // 32 spatial rows per block
  int s0 = qblk * 32;
  int tid = threadIdx.x;
  int w = tid >> 6;
  int lane = tid & 63;
  int l31 = lane & 31;
  int h = lane >> 5;
  int sp = s0 + l31;
  const _Float16* Ops[KS_];
#pragma unroll
  for (int s = 0; s < KS_; ++s) {
    int S = b * KS_ + s;
    Ops[s] = (S < 16) ? (OpA + (size_t)S * ((size_t)HW_ * CI_))
                      : (OpB + (size_t)(S - 16) * ((size_t)HW_ * CI_));
  }
  // per-lane merge weights (lane's row sp is fixed)
  float m[KS_], l[KS_], M = -1e30f;
#pragma unroll
  for (int s = 0; s < KS_; ++s) {
    float2 v = *(const float2*)&ml[((size_t)(b * KS_ + s) * HW_ + sp) * 2];
    m[s] = v.x;
    l[s] = v.y;
    M = fmaxf(M, m[s]);
  }
  float den = 0.f, wgt[KS_];
#pragma unroll
  for (int s = 0; s < KS_; ++s) {
    wgt[s] = exp2f(m[s] - M) * l[s];
    den += wgt[s];
  }
  float inv = 1.f / den;
  f16x2 wh[KS_];
#pragma unroll
  for (int s = 0; s < KS_; ++s) {
    _Float16 ws = (_Float16)(wgt[s] * inv);
    wh[s][0] = ws;
    wh[s][1] = ws;
  }
  // ---- phase 1: wave w merges k8 in {w*4 .. w*4+3} (via kk x h), once total ----
#pragma unroll
  for (int kk = 0; kk < 2; ++kk) {
    int k8 = w * 4 + kk * 2 + h;
    F4 a0, a1;
    a0.h2[0] = f16x2{0, 0}; a0.h2[1] = f16x2{0, 0};
    a1.h2[0] = f16x2{0, 0}; a1.h2[1] = f16x2{0, 0};
    size_t base = ((size_t)qblk * 32 + k8 * 2) * 32 + l31;
#pragma unroll
    for (int s = 0; s < KS_; ++s) {
      F4 v0, v1;
      v0.v = *(const f16x4*)&Ops[s][base * 4];
      v1.v = *(const f16x4*)&Ops[s][(base + 32) * 4];
      a0.h2[0] += wh[s] * v0.h2[0];
      a0.h2[1] += wh[s] * v0.h2[1];
      a1.h2[0] += wh[s] * v1.h2[0];
      a1.h2[1] += wh[s] * v1.h2[1];
    }
    *(f16x8*)&mrg[(k8 * 32 + l31) * 8] = cat8(a0.v, a1.v);
  }
  __syncthreads();
  // ---- phase 2: wave w owns channels [w*64, w*64+64): 8 ks x 2 mt MFMAs ----
  f32x16 acc[2];
#pragma unroll
  for (int i = 0; i < 2; ++i)
#pragma unroll
    for (int j = 0; j < 16; ++j) acc[i][j] = 0.f;
#pragma unroll
  for (int ks = 0; ks < 8; ++ks) {
    int k8 = ks * 2 + h;
    f16x8 bf = *(const f16x8*)&mrg[(k8 * 32 + l31) * 8];
#pragma unroll
    for (int mt = 0; mt < 2; ++mt) {
      int rblk = w * 2 + mt;
      f16x8 af = *(const f16x8*)&wo[((rblk * 16 + k8) * 32 + l31) * 8];
      acc[mt] = mfma16(af, bf, acc[mt]);
    }
  }
#pragma unroll
  for (int mt = 0; mt < 2; ++mt)
#pragma unroll
    for (int r = 0; r < 16; ++r) {
      int c = (w * 2 + mt) * 32 + (r & 3) + 8 * (r >> 2) + 4 * h;
      oc16[((size_t)(b * C_ + c)) * HW_ + sp] = (_Float16)(acc[mt][r] + ob[c]);
    }
}

// ---------------- K4: fused BN stats + BN + ReLU + residual, one block/channel. ----
__global__ __launch_bounds__(1024) void k4_bnfused(
    const _Float16* __restrict__ oc16, const float* __restrict__ x,
    const float* __restrict__ gamma, const float* __restrict__ beta,
    float* __restrict__ out) {
  int c = blockIdx.x;
  int t = threadIdx.x;  // 0..1023: 4 f16 per batch image
  f16x4 vv[B_];
  float s = 0.f, s2 = 0.f;
#pragma unroll
  for (int b = 0; b < B_; ++b) {
    vv[b] = *(const f16x4*)&oc16[((size_t)(b * C_ + c)) * HW_ + t * 4];
#pragma unroll
    for (int j = 0; j < 4; ++j) {
      float f = (float)vv[b][j];
      s += f;
      s2 += f * f;
    }
  }
#pragma unroll
  for (int mm = 1; mm < 64; mm <<= 1) {
    s += __shfl_xor(s, mm, 64);
    s2 += __shfl_xor(s2, mm, 64);
  }
  __shared__ float ls[32];
  __shared__ float mv[2];
  int w = t >> 6, lane = t & 63;
  if (lane == 0) {
    ls[w] = s;
    ls[16 + w] = s2;
  }
  __syncthreads();
  if (t == 0) {
    float a = 0.f, bb = 0.f;
#pragma unroll
    for (int i = 0; i < 16; ++i) {
      a += ls[i];
      bb += ls[16 + i];
    }
    float mean = a * (1.f / 16384.f);
    mv[0] = mean;
    mv[1] = bb * (1.f / 16384.f) - mean * mean;
  }
  __syncthreads();
  float mean = mv[0];
  float sc = gamma[c] * rsqrtf(mv[1] + 1e-5f);
  float bt = beta[c];
#pragma unroll
  for (int b = 0; b < B_; ++b) {
    size_t base = ((size_t)(b * C_ + c)) * HW_ + t * 4;
    f32x4 xv = *(const f32x4*)&x[base];
    f32x4 r;
#pragma unroll
    for (int j = 0; j < 4; ++j) {
      float y = ((float)vv[b][j] - mean) * sc + bt;
      y = fmaxf(y, 0.f);
      r[j] = y + xv[j];
    }
    *(f32x4*)&out[base] = r;
  }
}

extern "C" void kernel_launch(void* const* d_in, const int* in_sizes, int n_in,
                              void* d_out, int out_size, void* d_ws,
                              size_t ws_size, hipStream_t stream) {
  const float* x = (const float*)d_in[0];
  const float* g_w = (const float*)d_in[1];
  const float* g_b = (const float*)d_in[2];
  const float* th_w = (const float*)d_in[3];
  const float* th_b = (const float*)d_in[4];
  const float* ph_w = (const float*)d_in[5];
  const float* ph_b = (const float*)d_in[6];
  const float* o_w = (const float*)d_in[7];
  const float* o_b = (const float*)d_in[8];
  const float* gam = (const float*)d_in[9];
  const float* bet = (const float*)d_in[10];

  // Workspace map:
  //  [0,8M)    Opart chunks 16..23 (k2->k3)
  //  [8M,16M)  thetaP(8-12M)/phiP(12-16M) (k01->k2), then oc16 (k3->k4)
  //  [16M,20M) gP (k01->k2)
  //  [20M,..)  ml (768KB)
  //  [24M,..)  w16 (256KB, k0w->k01,k3)
  char* ws = (char*)d_ws;
  _Float16* OpB = (_Float16*)ws;                  // 8 MB: Opart chunks 16..23
  _Float16* oc16 = (_Float16*)(ws + 8388608);     // 8 MB f16 out-conv result
  _Float16* thetaP = (_Float16*)(ws + 8388608);   // 4 MB
  _Float16* phiP = (_Float16*)(ws + 12582912);    // 4 MB
  _Float16* gP = (_Float16*)(ws + 16777216);      // 4 MB
  float* ml = (float*)(ws + 20971520);            // 768 KB (24 splits)
  _Float16* w16 = (_Float16*)(ws + 25165824);     // 256 KB
  _Float16* OpA = (_Float16*)d_out;               // 16 MB: Opart chunks 0..15

  k0w_pack<<<64, 256, 0, stream>>>(th_w, ph_w, g_w, o_w, w16);
  k01_fused<<<dim3(64, 1, 4), 512, 0, stream>>>(x, w16, th_b, ph_b, g_b, thetaP,
                                                phiP, gP);
  k2_attn<<<dim3(32, KS_, 4), 256, 0, stream>>>(thetaP, phiP, gP, OpA, OpB, ml);
  k3_outconv<<<dim3(128, 1, 4), 256, 0, stream>>>(OpA, OpB, ml, w16 + 3 * 32768,
                                                  o_b, oc16);
  k4_bnfused<<<256, 1024, 0, stream>>>(oc16, x, gam, bet, (float*)d_out);
}